// Round 4
// baseline (340.645 us; speedup 1.0000x reference)
//
#include <hip/hip_runtime.h>

// Factorized Gumbel-max sampler — round 4: fully wave-synchronous (ZERO barriers).
//   d_in[0] q0     : float32 [8]       root table (wave-uniform -> s_load)
//   d_in[1] qg     : float32 [7*64]    conditional tables (per-WAVE LDS copy)
//   d_in[2] noise0 : float32 [N*8]     Gumbel noise, group 0
//   d_in[3] noise  : float32 [7*N*8]   Gumbel noise, groups 1..7
// Output: int32 [N*24] bits.
//
// R4: __syncthreads forces s_waitcnt vmcnt(0) (drains all 16 in-flight noise
// loads) — so eliminate ALL barriers: each wave stages its own table copy and
// transposes its own 64 samples in a private LDS region. Within-wave
// ds_write->ds_read needs only lgkmcnt, which the compiler handles. Loads all
// issued up-front; gather chain overlaps remaining loads via fine vmcnt.

#define NGROUPS 8

typedef float  f4  __attribute__((ext_vector_type(4)));
typedef int    i4  __attribute__((ext_vector_type(4)));

__global__ __launch_bounds__(256, 4) void fd_sample_kernel(
    const float* __restrict__ q0,
    const float* __restrict__ qg,
    const float* __restrict__ noise0,
    const float* __restrict__ noise,
    int* __restrict__ out,
    int N)
{
    // Per-wave private regions: no cross-wave hazards anywhere.
    __shared__ __align__(16) float s_tab[4 * 448];      // 4 waves x 1792 B table copy
    __shared__ unsigned int s_out[4 * 64 * 7];          // 4 waves x 64 samples x 7 dwords

    const int t    = threadIdx.x;
    const int wave = t >> 6;
    const int lane = t & 63;

    float* wtab        = s_tab + wave * 448;
    unsigned int* wout = s_out + wave * 448;            // 64*7 = 448 dwords

    // ---- Issue table-copy loads first (oldest in vmcnt queue) ----
    f4 t0 = ((const f4*)qg)[lane];                      // f4 slots 0..111
    f4 t1 = (lane < 48) ? ((const f4*)qg)[lane + 64] : t0;

    const int i  = blockIdx.x * blockDim.x + t;
    const int ii = (i < N) ? i : (N - 1);               // clamp (uniform work, no returns)

    // ---- Issue ALL 16 noise float4 loads up-front (one latency window) ----
    f4 nv[16];
    {
        const f4* p = (const f4*)noise0 + (size_t)ii * 2;
        nv[0] = __builtin_nontemporal_load(p);
        nv[1] = __builtin_nontemporal_load(p + 1);
    }
#pragma unroll
    for (int g = 1; g < NGROUPS; ++g) {
        const f4* p = (const f4*)noise + ((size_t)(g - 1) * N + ii) * 2;
        nv[2 * g]     = __builtin_nontemporal_load(p);
        nv[2 * g + 1] = __builtin_nontemporal_load(p + 1);
    }

    // ---- Stage this wave's table copy (waits only the 2 table loads: vmcnt(16)) ----
    ((f4*)wtab)[lane] = t0;
    if (lane < 48) ((f4*)wtab)[lane + 64] = t1;

    int idxs[NGROUPS];

    // ---- Group 0: argmax over q0 + noise0 (strict > == first-max, matches jnp.argmax) ----
    {
        f4 a = nv[0], b = nv[1];
        float n[8] = {a.x, a.y, a.z, a.w, b.x, b.y, b.z, b.w};
        float bv = q0[0] + n[0];
        int   bi = 0;
#pragma unroll
        for (int k = 1; k < 8; ++k) {
            float v = q0[k] + n[k];
            if (v > bv) { bv = v; bi = k; }
        }
        idxs[0] = bi;
    }

    // ---- Groups 1..7: per-wave LDS gather by previous idx, argmax ----
    // (8 distinct addrs/wave -> broadcast + 2-way max bank aliasing = free)
#pragma unroll
    for (int g = 1; g < NGROUPS; ++g) {
        const f4* tp = (const f4*)(wtab + (g - 1) * 64 + idxs[g - 1] * 8);   // 32B aligned
        f4 ta = tp[0], tb = tp[1];
        f4 na = nv[2 * g], nb = nv[2 * g + 1];
        float tt[8] = {ta.x, ta.y, ta.z, ta.w, tb.x, tb.y, tb.z, tb.w};
        float nn[8] = {na.x, na.y, na.z, na.w, nb.x, nb.y, nb.z, nb.w};

        float bv = tt[0] + nn[0];
        int   bi = 0;
#pragma unroll
        for (int k = 1; k < 8; ++k) {
            float v = tt[k] + nn[k];
            if (v > bv) { bv = v; bi = k; }
        }
        idxs[g] = bi;
    }

    // ---- Pack 24 bit-values as bytes into 6 dwords; stage in wave's LDS region ----
    {
        unsigned int by[24];
#pragma unroll
        for (int g = 0; g < NGROUPS; ++g) {
            by[g * 3 + 0] = (idxs[g] >> 2) & 1;
            by[g * 3 + 1] = (idxs[g] >> 1) & 1;
            by[g * 3 + 2] = idxs[g] & 1;
        }
#pragma unroll
        for (int d = 0; d < 6; ++d)                     // stride 7: write banks 7*lane+d, conflict-free
            wout[lane * 7 + d] = by[4 * d] | (by[4 * d + 1] << 8) |
                                 (by[4 * d + 2] << 16) | (by[4 * d + 3] << 24);
    }

    // ---- Per-wave transpose read-back + coalesced nt int4 stores (1 KB/instr) ----
    // Wave's out region: 64 samples x 6 int4. int4 k = j*64 + lane covers out
    // dwords 4k..4k+3 of the wave region -> sample s = k/6, dword e = k%6.
    const size_t wave_i4 = (size_t)blockIdx.x * 1536 + (size_t)wave * 384;
    const int    wave_s0 = blockIdx.x * 256 + wave * 64;
#pragma unroll
    for (int j = 0; j < 6; ++j) {
        int k = j * 64 + lane;
        int s = k / 6;
        int e = k - s * 6;
        unsigned int w = wout[s * 7 + e];
        if (wave_s0 + s < N) {
            i4 o = { (int)(w & 0xffu), (int)((w >> 8) & 0xffu),
                     (int)((w >> 16) & 0xffu), (int)(w >> 24) };
            __builtin_nontemporal_store(o, (i4*)out + wave_i4 + k);
        }
    }
}

extern "C" void kernel_launch(void* const* d_in, const int* in_sizes, int n_in,
                              void* d_out, int out_size, void* d_ws, size_t ws_size,
                              hipStream_t stream) {
    const float* q0     = (const float*)d_in[0];
    const float* qg     = (const float*)d_in[1];
    const float* noise0 = (const float*)d_in[2];
    const float* noise  = (const float*)d_in[3];
    int* out = (int*)d_out;

    const int N = in_sizes[2] / 8;  // noise0 is N*8 floats

    const int block = 256;
    const int grid  = (N + block - 1) / block;
    fd_sample_kernel<<<grid, block, 0, stream>>>(q0, qg, noise0, noise, out, N);
}